// Round 3
// baseline (239.180 us; speedup 1.0000x reference)
//
#include <hip/hip_runtime.h>

typedef __attribute__((ext_vector_type(8))) short short8;
typedef __attribute__((ext_vector_type(4))) float f32x4;

// ---- problem constants ----
#define NSPAN 1024
#define DDIM  512
#define HDIM  150
#define HPAD  160
#define WINW  250
#define OUTW  251

// ---- LDS layout (pair_main), bytes ----
// GEMM1 phase: B1 dbuf @0 / @10240 (160 rows x 64B each)
//              A1 dbuf @20480 / @28672 (128 rows x 64B each)
//              gi (g_i row f32[512]) @36864 (2048)         -> 38912 in use
// GEMM2 phase: A2 (h1 bf16 [128] rows x 320B) @0 (40960)   -> overwrites GEMM1 bufs
// GEMM3 phase: sL (f32[128]) @0                            -> overwrites A2 row 0
#define B1_OFF0 0
#define B1_OFF1 10240
#define A1_OFF0 20480
#define A1_OFF1 28672
#define GI_OFF  36864
#define SMEM_BYTES 40960

__device__ __forceinline__ unsigned short f2bf(float x) {
  union { float f; unsigned int u; } v; v.f = x;
  return (unsigned short)((v.u + 0x7fffu + ((v.u >> 16) & 1u)) >> 16);
}

// v_cvt_pk_bf16_f32: dst = {lo16=bf16(a), hi16=bf16(b)}, RNE
__device__ __forceinline__ unsigned int cvtpk(float a, float b) {
  unsigned int r;
  asm("v_cvt_pk_bf16_f32 %0, %1, %2" : "=v"(r) : "v"(a), "v"(b));
  return r;
}

__device__ __forceinline__ void gload_lds16(const void* g, void* l) {
  __builtin_amdgcn_global_load_lds(
      (const __attribute__((address_space(1))) unsigned int*)g,
      (__attribute__((address_space(3))) unsigned int*)l, 16, 0, 0);
}

// ---------------- prep: pre1 = g@W1a + b1, gjb = g@W1b (fp32, exact) ----------------
// grid: 1024 blocks = 512 i-groups(2 rows) x 2 (which), block 192 threads
__global__ __launch_bounds__(192) void prep_gemm(
    const float* __restrict__ g, const float* __restrict__ W1,
    const float* __restrict__ b1, float* __restrict__ pre1,
    float* __restrict__ gjb)
{
  __shared__ __align__(16) float gs[2 * DDIM];
  const int grp = blockIdx.x >> 1;
  const int which = blockIdx.x & 1;
  const int i0 = grp << 1;
  for (int idx = threadIdx.x; idx < (2 * DDIM / 4); idx += 192)
    ((float4*)gs)[idx] = ((const float4*)(g + (size_t)i0 * DDIM))[idx];
  __syncthreads();
  const int n = threadIdx.x;
  float a0 = 0.f, a1 = 0.f;
  if (n < HDIM) {
    const float* Wp = W1 + (size_t)which * DDIM * HDIM + n;
#pragma unroll 8
    for (int d = 0; d < DDIM; ++d) {
      float w = Wp[(size_t)d * HDIM];
      a0 += gs[d] * w;
      a1 += gs[DDIM + d] * w;
    }
  }
  if (n < HPAD) {
    float* dst = which ? gjb : pre1;
    float add = (which == 0 && n < HDIM) ? b1[n] : 0.f;
    float v0 = (n < HDIM) ? (a0 + add) : 0.f;
    float v1 = (n < HDIM) ? (a1 + add) : 0.f;
    dst[(size_t)i0 * HPAD + n] = v0;
    dst[(size_t)(i0 + 1) * HPAD + n] = v1;
  }
}

// ---------------- prep: transpose + bf16 convert W1c, W2; pad W3 ----------------
__global__ void prep_misc(const float* __restrict__ W1, const float* __restrict__ W2,
                          const float* __restrict__ W3,
                          unsigned short* __restrict__ w1cT,
                          unsigned short* __restrict__ w2T,
                          float* __restrict__ w3p)
{
  int id = blockIdx.x * 256 + threadIdx.x;
  if (id < HPAD * DDIM) {                       // 81920
    int n = id >> 9, d = id & 511;
    float v = (n < HDIM) ? W1[(size_t)(2 * DDIM + d) * HDIM + n] : 0.f;
    w1cT[id] = f2bf(v);
  } else if (id < HPAD * DDIM + HPAD * HPAD) {  // +25600
    int id2 = id - HPAD * DDIM;
    int n = id2 / HPAD, k = id2 % HPAD;
    float v = (n < HDIM && k < HDIM) ? W2[(size_t)k * HDIM + n] : 0.f;
    w2T[id2] = f2bf(v);
  } else if (id < HPAD * DDIM + HPAD * HPAD + HPAD) {
    int n = id - HPAD * DDIM - HPAD * HPAD;
    w3p[n] = (n < HDIM) ? W3[n] : 0.f;
  }
}

// ---------------- main fused kernel ----------------
// block = (i, half): 128 window rows. 4 waves, each owns rows [wv*32, wv*32+32).
__global__ __launch_bounds__(256, 4) void pair_main(
    const float* __restrict__ g, const float* __restrict__ sm,
    const float* __restrict__ pre1, const float* __restrict__ gjb,
    const unsigned short* __restrict__ w1cT, const unsigned short* __restrict__ w2T,
    const float* __restrict__ w3p, const float* __restrict__ b2,
    const float* __restrict__ b3, float* __restrict__ out)
{
  __shared__ __align__(16) char smem[SMEM_BYTES];
  const int tid = threadIdx.x;
  const int lane = tid & 63;
  const int wv = tid >> 6;
  const int l15 = lane & 15;
  const int lq = lane >> 4;          // 0..3
  const int i = blockIdx.x >> 1;
  const int mbase = (blockIdx.x & 1) << 7;

  // stage g_i row (512 f32) into LDS
  float* giL = (float*)(smem + GI_OFF);
  if (tid < 128)
    ((float4*)giL)[tid] = ((const float4*)(g + (size_t)i * DDIM))[tid];

  // A1 staging setup: thread -> (row, 16-col half)
  const int r_s = tid >> 1;
  const int kh = (tid & 1) << 4;     // 0 or 16
  const int j_s = i - WINW + mbase + r_s;
  const int jc_s = j_s < 0 ? 0 : (j_s > NSPAN - 1 ? NSPAN - 1 : j_s);
  const float4* gj4 = (const float4*)(g + (size_t)jc_s * DDIM);
  const int swA = ((r_s >> 1) & 7) << 4;
  const int stA0 = (((r_s << 6) + (kh << 1)) ^ swA);
  const int stA1 = (((r_s << 6) + (kh << 1) + 16) ^ swA);

  // B1 global_load_lds: per-lane inverse-swizzled source byte offsets (k0=0)
  // wave w covers LDS bytes [w*2560, (w+1)*2560): t=0,1 full-wave, t=2 half-wave
  unsigned int bsrc[3];
#pragma unroll
  for (int t = 0; t < 3; ++t) {
    int b = wv * 2560 + (t << 10) + (lane << 4);
    int m = b >> 7;                       // 128B row-pair block
    int bp = b ^ ((m & 7) << 4);          // involution within block
    int n = bp >> 6, o = bp & 63;
    bsrc[t] = (unsigned int)(n * 1024 + o);   // + k0*2 at use (w1cT row = 1024B)
  }

  // fragment read addresses (relative to buffer base; 64B-stride, pair-XOR swizzle)
  int xa[2];
#pragma unroll
  for (int mt = 0; mt < 2; ++mt) {
    int row = (wv << 5) + (mt << 4) + l15;
    xa[mt] = ((row << 6) + (lq << 4)) ^ (((row >> 1) & 7) << 4);
  }
  int xb[10];
#pragma unroll
  for (int nt = 0; nt < 10; ++nt) {
    int nr = (nt << 4) + l15;
    xb[nt] = ((nr << 6) + (lq << 4)) ^ (((nr >> 1) & 7) << 4);
  }

  f32x4 acc[2][10];
#pragma unroll
  for (int mt = 0; mt < 2; ++mt)
#pragma unroll
    for (int nt = 0; nt < 10; ++nt)
      acc[mt][nt] = (f32x4){0.f, 0.f, 0.f, 0.f};

  const char* w1cB = (const char*)w1cT;
  __syncthreads();   // giL ready

  // ---- GEMM1: [128 x 512] (g_i*g_j bf16) @ [512 x 160] (W1c), dbuf, 1 barrier/step ----
  for (int s = 0; s < 16; ++s) {
    const int k0 = s << 5;
    char* a1b = smem + ((s & 1) ? A1_OFF1 : A1_OFF0);
    char* b1b = smem + ((s & 1) ? B1_OFF1 : B1_OFF0);

    // stage B1[cur]: direct global->LDS (linear dest, pre-swizzled source)
    {
      char* ldsw = b1b + wv * 2560;
      gload_lds16(w1cB + bsrc[0] + (k0 << 1), ldsw);
      gload_lds16(w1cB + bsrc[1] + (k0 << 1), ldsw + 1024);
      if (lane < 32)
        gload_lds16(w1cB + bsrc[2] + (k0 << 1), ldsw + 2048);
    }
    // stage A1[cur]: products -> bf16, swizzled
    {
      const int fb = (k0 + kh) >> 2;
      float4 x0 = gj4[fb], x1 = gj4[fb + 1], x2 = gj4[fb + 2], x3 = gj4[fb + 3];
      const float4* gi4 = ((const float4*)giL) + fb;
      float4 y0 = gi4[0], y1 = gi4[1], y2 = gi4[2], y3 = gi4[3];
      uint4 w0, w1;
      w0.x = cvtpk(x0.x * y0.x, x0.y * y0.y);
      w0.y = cvtpk(x0.z * y0.z, x0.w * y0.w);
      w0.z = cvtpk(x1.x * y1.x, x1.y * y1.y);
      w0.w = cvtpk(x1.z * y1.z, x1.w * y1.w);
      w1.x = cvtpk(x2.x * y2.x, x2.y * y2.y);
      w1.y = cvtpk(x2.z * y2.z, x2.w * y2.w);
      w1.z = cvtpk(x3.x * y3.x, x3.y * y3.y);
      w1.w = cvtpk(x3.z * y3.z, x3.w * y3.w);
      *(uint4*)(a1b + stA0) = w0;
      *(uint4*)(a1b + stA1) = w1;
    }
    __syncthreads();   // drains vmcnt (gload_lds) + lgkm; LDS[cur] ready
    short8 a0 = *(const short8*)(a1b + xa[0]);
    short8 a1 = *(const short8*)(a1b + xa[1]);
#pragma unroll
    for (int nt = 0; nt < 10; ++nt) {
      short8 bb = *(const short8*)(b1b + xb[nt]);
      acc[0][nt] = __builtin_amdgcn_mfma_f32_16x16x32_bf16(a0, bb, acc[0][nt], 0, 0, 0);
      acc[1][nt] = __builtin_amdgcn_mfma_f32_16x16x32_bf16(a1, bb, acc[1][nt], 0, 0, 0);
    }
    // no trailing barrier: next step writes the other buffer; reuse distance = 2 barriers
  }
  __syncthreads();   // protect last step's bufs before A2 overwrites [0,40960)

  // ---- epilogue 1: h1 = relu(acc + pre1_i + gjb_j) -> A2 @0 (bf16, swizzled) ----
  float p1v[10];
#pragma unroll
  for (int nt = 0; nt < 10; ++nt)
    p1v[nt] = pre1[(size_t)i * HPAD + (nt << 4) + l15];

#pragma unroll
  for (int mt = 0; mt < 2; ++mt) {
#pragma unroll
    for (int rr = 0; rr < 4; ++rr) {
      const int row = (wv << 5) + (mt << 4) + (lq << 2) + rr;
      int j = i - WINW + mbase + row;
      j = j < 0 ? 0 : (j > NSPAN - 1 ? NSPAN - 1 : j);
      const float* gjr = gjb + (size_t)j * HPAD;
      const int sw = ((row + (row >> 2)) & 3) << 4;
      const int rb = row * 320;
#pragma unroll
      for (int np = 0; np < 5; ++np) {
        const int n0 = np << 1, n1 = n0 + 1;
        float v0 = fmaxf(acc[mt][n0][rr] + p1v[n0] + gjr[(n0 << 4) + l15], 0.f);
        float v1 = fmaxf(acc[mt][n1][rr] + p1v[n1] + gjr[(n1 << 4) + l15], 0.f);
        unsigned int u = cvtpk(v0, v1);
        *(unsigned short*)(smem + ((rb + (((n0 << 4) + l15) << 1)) ^ sw)) = (unsigned short)u;
        *(unsigned short*)(smem + ((rb + (((n1 << 4) + l15) << 1)) ^ sw)) = (unsigned short)(u >> 16);
      }
    }
  }

  // ---- GEMM2: [128 x 160] (h1 from LDS) @ [160 x 160] (W2 frags direct from L2) ----
  f32x4 acc2[2][10];
#pragma unroll
  for (int mt = 0; mt < 2; ++mt)
#pragma unroll
    for (int nt = 0; nt < 10; ++nt)
      acc2[mt][nt] = (f32x4){0.f, 0.f, 0.f, 0.f};

  int ya[2];
#pragma unroll
  for (int mt = 0; mt < 2; ++mt) {
    int row = (wv << 5) + (mt << 4) + l15;
    ya[mt] = ((row * 320) + (lq << 4)) ^ (((row + (row >> 2)) & 3) << 4);
  }

  __syncthreads();   // A2 fully written

#pragma unroll
  for (int c = 0; c < 5; ++c) {
    short8 a0 = *(const short8*)(smem + ya[0] + (c << 6));
    short8 a1 = *(const short8*)(smem + ya[1] + (c << 6));
#pragma unroll
    for (int nt = 0; nt < 10; ++nt) {
      short8 bb = *(const short8*)(w2T + (size_t)((nt << 4) + l15) * HPAD + (c << 5) + (lq << 3));
      acc2[0][nt] = __builtin_amdgcn_mfma_f32_16x16x32_bf16(a0, bb, acc2[0][nt], 0, 0, 0);
      acc2[1][nt] = __builtin_amdgcn_mfma_f32_16x16x32_bf16(a1, bb, acc2[1][nt], 0, 0, 0);
    }
  }
  __syncthreads();   // all A2 reads done before sL overwrites bytes [0,512)

  // ---- GEMM3: s = relu(acc2 + b2) @ W3, 16-lane shuffle reduce ----
  float w3v[10], b2v[10];
#pragma unroll
  for (int nt = 0; nt < 10; ++nt) {
    int nn = (nt << 4) + l15;
    w3v[nt] = w3p[nn];
    b2v[nt] = (nn < HDIM) ? b2[nn] : 0.f;
  }
  float* sL = (float*)smem;
#pragma unroll
  for (int mt = 0; mt < 2; ++mt) {
#pragma unroll
    for (int rr = 0; rr < 4; ++rr) {
      float part = 0.f;
#pragma unroll
      for (int nt = 0; nt < 10; ++nt) {
        float h2 = fmaxf(acc2[mt][nt][rr] + b2v[nt], 0.f);
        part = fmaf(h2, w3v[nt], part);
      }
      part += __shfl_xor(part, 1);
      part += __shfl_xor(part, 2);
      part += __shfl_xor(part, 4);
      part += __shfl_xor(part, 8);
      if (l15 == 0)
        sL[(wv << 5) + (mt << 4) + (lq << 2) + rr] = part;
    }
  }
  __syncthreads();

  // ---- final: sij = sm_i + sm_j + s + b3, masked; epsilon col = 0 ----
  if (tid < 128) {
    const int rg = mbase + tid;
    if (rg <= WINW) {
      const int j = i - WINW + rg;
      float v = 0.f;
      if (rg < WINW && j >= 0)
        v = sL[tid] + b3[0] + sm[i] + sm[j];
      out[(size_t)i * OUTW + rg] = v;
    }
  }
}

extern "C" void kernel_launch(void* const* d_in, const int* in_sizes, int n_in,
                              void* d_out, int out_size, void* d_ws, size_t ws_size,
                              hipStream_t stream) {
  const float* g  = (const float*)d_in[0];
  const float* sm = (const float*)d_in[1];
  const float* W1 = (const float*)d_in[2];
  const float* b1 = (const float*)d_in[3];
  const float* W2 = (const float*)d_in[4];
  const float* b2 = (const float*)d_in[5];
  const float* W3 = (const float*)d_in[6];
  const float* b3 = (const float*)d_in[7];
  float* out = (float*)d_out;

  // workspace carve (total 1,526,400 B)
  char* ws = (char*)d_ws;
  float* pre1          = (float*)ws;                         // 1024*160*4 = 655360
  float* gjb           = (float*)(ws + 655360);              // 655360
  unsigned short* w1cT = (unsigned short*)(ws + 1310720);    // 160*512*2 = 163840
  unsigned short* w2T  = (unsigned short*)(ws + 1474560);    // 160*160*2 = 51200
  float* w3p           = (float*)(ws + 1525760);             // 640

  prep_gemm<<<1024, 192, 0, stream>>>(g, W1, b1, pre1, gjb);
  prep_misc<<<(HPAD * DDIM + HPAD * HPAD + HPAD + 255) / 256, 256, 0, stream>>>(
      W1, W2, W3, w1cT, w2T, w3p);
  pair_main<<<2048, 256, 0, stream>>>(g, sm, pre1, gjb, w1cT, w2T, w3p, b2, b3, out);
}

// Round 4
// 191.501 us; speedup vs baseline: 1.2490x; 1.2490x over previous
//
#include <hip/hip_runtime.h>

typedef __attribute__((ext_vector_type(8))) short short8;
typedef __attribute__((ext_vector_type(4))) float f32x4;

// ---- problem constants ----
#define NSPAN 1024
#define DDIM  512
#define HDIM  150
#define HPAD  160
#define WINW  250
#define OUTW  251

// ---- LDS layout (pair_main), bytes ----
// GEMM1 phase: B1 dbuf @0 / @10240 (160 rows x 64B each)
//              A1 dbuf @20480 / @28672 (128 rows x 64B each)
//              gi (g_i row f32[512]) @36864 (2048)         -> 38912 in use
// GEMM2 phase: A2 (h1 bf16 [128] rows x 320B) @0 (40960)   -> overwrites GEMM1 bufs
// GEMM3 phase: sL (f32[128]) @0                            -> overwrites A2 row 0
#define B1_OFF0 0
#define B1_OFF1 10240
#define A1_OFF0 20480
#define A1_OFF1 28672
#define GI_OFF  36864
#define SMEM_BYTES 40960

__device__ __forceinline__ unsigned short f2bf(float x) {
  union { float f; unsigned int u; } v; v.f = x;
  return (unsigned short)((v.u + 0x7fffu + ((v.u >> 16) & 1u)) >> 16);
}

// v_cvt_pk_bf16_f32: dst = {lo16=bf16(a), hi16=bf16(b)}, RNE
__device__ __forceinline__ unsigned int cvtpk(float a, float b) {
  unsigned int r;
  asm("v_cvt_pk_bf16_f32 %0, %1, %2" : "=v"(r) : "v"(a), "v"(b));
  return r;
}

__device__ __forceinline__ void gload_lds16(const void* g, void* l) {
  __builtin_amdgcn_global_load_lds(
      (const __attribute__((address_space(1))) unsigned int*)g,
      (__attribute__((address_space(3))) unsigned int*)l, 16, 0, 0);
}

// ---------------- prep: pre1 = g@W1a + b1, gjb = g@W1b (fp32, exact) ----------------
// grid: 1024 blocks = 512 i-groups(2 rows) x 2 (which), block 192 threads
__global__ __launch_bounds__(192) void prep_gemm(
    const float* __restrict__ g, const float* __restrict__ W1,
    const float* __restrict__ b1, float* __restrict__ pre1,
    float* __restrict__ gjb)
{
  __shared__ __align__(16) float gs[2 * DDIM];
  const int grp = blockIdx.x >> 1;
  const int which = blockIdx.x & 1;
  const int i0 = grp << 1;
  for (int idx = threadIdx.x; idx < (2 * DDIM / 4); idx += 192)
    ((float4*)gs)[idx] = ((const float4*)(g + (size_t)i0 * DDIM))[idx];
  __syncthreads();
  const int n = threadIdx.x;
  float a0 = 0.f, a1 = 0.f;
  if (n < HDIM) {
    const float* Wp = W1 + (size_t)which * DDIM * HDIM + n;
#pragma unroll 8
    for (int d = 0; d < DDIM; ++d) {
      float w = Wp[(size_t)d * HDIM];
      a0 += gs[d] * w;
      a1 += gs[DDIM + d] * w;
    }
  }
  if (n < HPAD) {
    float* dst = which ? gjb : pre1;
    float add = (which == 0 && n < HDIM) ? b1[n] : 0.f;
    float v0 = (n < HDIM) ? (a0 + add) : 0.f;
    float v1 = (n < HDIM) ? (a1 + add) : 0.f;
    dst[(size_t)i0 * HPAD + n] = v0;
    dst[(size_t)(i0 + 1) * HPAD + n] = v1;
  }
}

// ---------------- prep: transpose + bf16 convert W1c, W2; pad W3 ----------------
// coalesced-read mapping: consecutive threads read consecutive source elements;
// scattered writes land in L2 (dest buffers are small and stay hot).
__global__ void prep_misc(const float* __restrict__ W1, const float* __restrict__ W2,
                          const float* __restrict__ W3,
                          unsigned short* __restrict__ w1cT,
                          unsigned short* __restrict__ w2T,
                          float* __restrict__ w3p)
{
  int id = blockIdx.x * 256 + threadIdx.x;
  if (id < HPAD * DDIM) {                       // 81920: id = d*160 + n
    int d = id / HPAD, n = id % HPAD;
    float v = (n < HDIM) ? W1[(size_t)(2 * DDIM + d) * HDIM + n] : 0.f;
    w1cT[(size_t)n * DDIM + d] = f2bf(v);
  } else if (id < HPAD * DDIM + HPAD * HPAD) {  // +25600: id2 = k*160 + n
    int id2 = id - HPAD * DDIM;
    int k = id2 / HPAD, n = id2 % HPAD;
    float v = (n < HDIM && k < HDIM) ? W2[(size_t)k * HDIM + n] : 0.f;
    w2T[(size_t)n * HPAD + k] = f2bf(v);
  } else if (id < HPAD * DDIM + HPAD * HPAD + HPAD) {
    int n = id - HPAD * DDIM - HPAD * HPAD;
    w3p[n] = (n < HDIM) ? W3[n] : 0.f;
  }
}

// ---------------- main fused kernel ----------------
// block = (i, half): 128 window rows. 4 waves, each owns rows [wv*32, wv*32+32).
// __launch_bounds__(256,3): 3 blocks/CU -> ~170-reg budget/wave, fits 80 AGPR acc
// + ~64 arch VGPR without spilling (round-3's (256,4) spilled: 64 MB WRITE_SIZE).
__global__ __launch_bounds__(256, 3) void pair_main(
    const float* __restrict__ g, const float* __restrict__ sm,
    const float* __restrict__ pre1, const float* __restrict__ gjb,
    const unsigned short* __restrict__ w1cT, const unsigned short* __restrict__ w2T,
    const float* __restrict__ w3p, const float* __restrict__ b2,
    const float* __restrict__ b3, float* __restrict__ out)
{
  __shared__ __align__(16) char smem[SMEM_BYTES];
  const int tid = threadIdx.x;
  const int lane = tid & 63;
  const int wv = tid >> 6;
  const int l15 = lane & 15;
  const int lq = lane >> 4;          // 0..3
  const int i = blockIdx.x >> 1;
  const int mbase = (blockIdx.x & 1) << 7;

  // stage g_i row (512 f32) into LDS
  float* giL = (float*)(smem + GI_OFF);
  if (tid < 128)
    ((float4*)giL)[tid] = ((const float4*)(g + (size_t)i * DDIM))[tid];

  // A1 staging setup: thread -> (row, 16-col half)
  const int r_s = tid >> 1;
  const int kh = (tid & 1) << 4;     // 0 or 16
  const int j_s = i - WINW + mbase + r_s;
  const int jc_s = j_s < 0 ? 0 : (j_s > NSPAN - 1 ? NSPAN - 1 : j_s);
  const float4* gj4 = (const float4*)(g + (size_t)jc_s * DDIM);
  const int swA = ((r_s >> 1) & 7) << 4;
  const int stA0 = (((r_s << 6) + (kh << 1)) ^ swA);
  const int stA1 = (((r_s << 6) + (kh << 1) + 16) ^ swA);

  // B1 global_load_lds: per-lane inverse-swizzled source byte offsets (k0=0)
  // wave w covers LDS bytes [w*2560, (w+1)*2560): t=0,1 full-wave, t=2 half-wave
  unsigned int bsrc[3];
#pragma unroll
  for (int t = 0; t < 3; ++t) {
    int b = wv * 2560 + (t << 10) + (lane << 4);
    int m = b >> 7;                       // 128B row-pair block
    int bp = b ^ ((m & 7) << 4);          // involution within block
    int n = bp >> 6, o = bp & 63;
    bsrc[t] = (unsigned int)(n * 1024 + o);   // + k0*2 at use (w1cT row = 1024B)
  }

  // fragment read addresses (relative to buffer base; 64B-stride, pair-XOR swizzle)
  int xa[2];
#pragma unroll
  for (int mt = 0; mt < 2; ++mt) {
    int row = (wv << 5) + (mt << 4) + l15;
    xa[mt] = ((row << 6) + (lq << 4)) ^ (((row >> 1) & 7) << 4);
  }
  int xb[10];
#pragma unroll
  for (int nt = 0; nt < 10; ++nt) {
    int nr = (nt << 4) + l15;
    xb[nt] = ((nr << 6) + (lq << 4)) ^ (((nr >> 1) & 7) << 4);
  }

  f32x4 acc[2][10];
#pragma unroll
  for (int mt = 0; mt < 2; ++mt)
#pragma unroll
    for (int nt = 0; nt < 10; ++nt)
      acc[mt][nt] = (f32x4){0.f, 0.f, 0.f, 0.f};

  const char* w1cB = (const char*)w1cT;
  __syncthreads();   // giL ready

  // ---- GEMM1: [128 x 512] (g_i*g_j bf16) @ [512 x 160] (W1c), dbuf, 1 barrier/step ----
  for (int s = 0; s < 16; ++s) {
    const int k0 = s << 5;
    char* a1b = smem + ((s & 1) ? A1_OFF1 : A1_OFF0);
    char* b1b = smem + ((s & 1) ? B1_OFF1 : B1_OFF0);

    // stage B1[cur]: direct global->LDS (linear dest, pre-swizzled source)
    {
      char* ldsw = b1b + wv * 2560;
      gload_lds16(w1cB + bsrc[0] + (k0 << 1), ldsw);
      gload_lds16(w1cB + bsrc[1] + (k0 << 1), ldsw + 1024);
      if (lane < 32)
        gload_lds16(w1cB + bsrc[2] + (k0 << 1), ldsw + 2048);
    }
    // stage A1[cur]: products -> bf16, swizzled
    {
      const int fb = (k0 + kh) >> 2;
      float4 x0 = gj4[fb], x1 = gj4[fb + 1], x2 = gj4[fb + 2], x3 = gj4[fb + 3];
      const float4* gi4 = ((const float4*)giL) + fb;
      float4 y0 = gi4[0], y1 = gi4[1], y2 = gi4[2], y3 = gi4[3];
      uint4 w0, w1;
      w0.x = cvtpk(x0.x * y0.x, x0.y * y0.y);
      w0.y = cvtpk(x0.z * y0.z, x0.w * y0.w);
      w0.z = cvtpk(x1.x * y1.x, x1.y * y1.y);
      w0.w = cvtpk(x1.z * y1.z, x1.w * y1.w);
      w1.x = cvtpk(x2.x * y2.x, x2.y * y2.y);
      w1.y = cvtpk(x2.z * y2.z, x2.w * y2.w);
      w1.z = cvtpk(x3.x * y3.x, x3.y * y3.y);
      w1.w = cvtpk(x3.z * y3.z, x3.w * y3.w);
      *(uint4*)(a1b + stA0) = w0;
      *(uint4*)(a1b + stA1) = w1;
    }
    __syncthreads();   // drains vmcnt (gload_lds) + lgkm; LDS[cur] ready
    short8 a0 = *(const short8*)(a1b + xa[0]);
    short8 a1 = *(const short8*)(a1b + xa[1]);
#pragma unroll
    for (int nt = 0; nt < 10; ++nt) {
      short8 bb = *(const short8*)(b1b + xb[nt]);
      acc[0][nt] = __builtin_amdgcn_mfma_f32_16x16x32_bf16(a0, bb, acc[0][nt], 0, 0, 0);
      acc[1][nt] = __builtin_amdgcn_mfma_f32_16x16x32_bf16(a1, bb, acc[1][nt], 0, 0, 0);
    }
    // no trailing barrier: next step writes the other buffer; reuse distance = 2 barriers
  }
  __syncthreads();   // protect last step's bufs before A2 overwrites [0,40960)

  // ---- epilogue 1: h1 = relu(acc + pre1_i + gjb_j) -> A2 @0 (bf16, swizzled) ----
  float p1v[10];
#pragma unroll
  for (int nt = 0; nt < 10; ++nt)
    p1v[nt] = pre1[(size_t)i * HPAD + (nt << 4) + l15];

#pragma unroll
  for (int mt = 0; mt < 2; ++mt) {
#pragma unroll
    for (int rr = 0; rr < 4; ++rr) {
      const int row = (wv << 5) + (mt << 4) + (lq << 2) + rr;
      int j = i - WINW + mbase + row;
      j = j < 0 ? 0 : (j > NSPAN - 1 ? NSPAN - 1 : j);
      const float* gjr = gjb + (size_t)j * HPAD;
      const int sw = ((row + (row >> 2)) & 3) << 4;
      const int rb = row * 320;
#pragma unroll
      for (int np = 0; np < 5; ++np) {
        const int n0 = np << 1, n1 = n0 + 1;
        float v0 = fmaxf(acc[mt][n0][rr] + p1v[n0] + gjr[(n0 << 4) + l15], 0.f);
        float v1 = fmaxf(acc[mt][n1][rr] + p1v[n1] + gjr[(n1 << 4) + l15], 0.f);
        unsigned int u = cvtpk(v0, v1);
        *(unsigned short*)(smem + ((rb + (((n0 << 4) + l15) << 1)) ^ sw)) = (unsigned short)u;
        *(unsigned short*)(smem + ((rb + (((n1 << 4) + l15) << 1)) ^ sw)) = (unsigned short)(u >> 16);
      }
    }
  }

  // ---- GEMM2: [128 x 160] (h1 from LDS) @ [160 x 160] (W2 frags direct from L2) ----
  // reuse acc[][] as the GEMM2 accumulator (lifetimes disjoint; keeps peak regs low)
  int ya[2];
#pragma unroll
  for (int mt = 0; mt < 2; ++mt) {
    int row = (wv << 5) + (mt << 4) + l15;
    ya[mt] = ((row * 320) + (lq << 4)) ^ (((row + (row >> 2)) & 3) << 4);
  }

  __syncthreads();   // A2 fully written

#pragma unroll
  for (int mt = 0; mt < 2; ++mt)
#pragma unroll
    for (int nt = 0; nt < 10; ++nt)
      acc[mt][nt] = (f32x4){0.f, 0.f, 0.f, 0.f};

#pragma unroll
  for (int c = 0; c < 5; ++c) {
    short8 a0 = *(const short8*)(smem + ya[0] + (c << 6));
    short8 a1 = *(const short8*)(smem + ya[1] + (c << 6));
#pragma unroll
    for (int nt = 0; nt < 10; ++nt) {
      short8 bb = *(const short8*)(w2T + (size_t)((nt << 4) + l15) * HPAD + (c << 5) + (lq << 3));
      acc[0][nt] = __builtin_amdgcn_mfma_f32_16x16x32_bf16(a0, bb, acc[0][nt], 0, 0, 0);
      acc[1][nt] = __builtin_amdgcn_mfma_f32_16x16x32_bf16(a1, bb, acc[1][nt], 0, 0, 0);
    }
  }
  __syncthreads();   // all A2 reads done before sL overwrites bytes [0,512)

  // ---- GEMM3: s = relu(acc + b2) @ W3, 16-lane shuffle reduce ----
  float w3v[10], b2v[10];
#pragma unroll
  for (int nt = 0; nt < 10; ++nt) {
    int nn = (nt << 4) + l15;
    w3v[nt] = w3p[nn];
    b2v[nt] = (nn < HDIM) ? b2[nn] : 0.f;
  }
  float* sL = (float*)smem;
#pragma unroll
  for (int mt = 0; mt < 2; ++mt) {
#pragma unroll
    for (int rr = 0; rr < 4; ++rr) {
      float part = 0.f;
#pragma unroll
      for (int nt = 0; nt < 10; ++nt) {
        float h2 = fmaxf(acc[mt][nt][rr] + b2v[nt], 0.f);
        part = fmaf(h2, w3v[nt], part);
      }
      part += __shfl_xor(part, 1);
      part += __shfl_xor(part, 2);
      part += __shfl_xor(part, 4);
      part += __shfl_xor(part, 8);
      if (l15 == 0)
        sL[(wv << 5) + (mt << 4) + (lq << 2) + rr] = part;
    }
  }
  __syncthreads();

  // ---- final: sij = sm_i + sm_j + s + b3, masked; epsilon col = 0 ----
  if (tid < 128) {
    const int rg = mbase + tid;
    if (rg <= WINW) {
      const int j = i - WINW + rg;
      float v = 0.f;
      if (rg < WINW && j >= 0)
        v = sL[tid] + b3[0] + sm[i] + sm[j];
      out[(size_t)i * OUTW + rg] = v;
    }
  }
}

extern "C" void kernel_launch(void* const* d_in, const int* in_sizes, int n_in,
                              void* d_out, int out_size, void* d_ws, size_t ws_size,
                              hipStream_t stream) {
  const float* g  = (const float*)d_in[0];
  const float* sm = (const float*)d_in[1];
  const float* W1 = (const float*)d_in[2];
  const float* b1 = (const float*)d_in[3];
  const float* W2 = (const float*)d_in[4];
  const float* b2 = (const float*)d_in[5];
  const float* W3 = (const float*)d_in[6];
  const float* b3 = (const float*)d_in[7];
  float* out = (float*)d_out;

  // workspace carve (total 1,526,400 B)
  char* ws = (char*)d_ws;
  float* pre1          = (float*)ws;                         // 1024*160*4 = 655360
  float* gjb           = (float*)(ws + 655360);              // 655360
  unsigned short* w1cT = (unsigned short*)(ws + 1310720);    // 160*512*2 = 163840
  unsigned short* w2T  = (unsigned short*)(ws + 1474560);    // 160*160*2 = 51200
  float* w3p           = (float*)(ws + 1525760);             // 640

  prep_gemm<<<1024, 192, 0, stream>>>(g, W1, b1, pre1, gjb);
  prep_misc<<<(HPAD * DDIM + HPAD * HPAD + HPAD + 255) / 256, 256, 0, stream>>>(
      W1, W2, W3, w1cT, w2T, w3p);
  pair_main<<<2048, 256, 0, stream>>>(g, sm, pre1, gjb, w1cT, w2T, w3p, b2, b3, out);
}